// Round 1
// baseline (1246.385 us; speedup 1.0000x reference)
//
#include <hip/hip_runtime.h>
#include <hip/hip_bf16.h>

#define NN 4096

typedef unsigned short u16;
using bf16x8 = __attribute__((ext_vector_type(8))) short;
using f32x4  = __attribute__((ext_vector_type(4))) float;
using u32x4  = __attribute__((ext_vector_type(4))) unsigned int;

// round-to-nearest-even f32 -> bf16 bits
__device__ inline u16 f2bf(float f) {
    union { float f; unsigned u; } c; c.f = f;
    unsigned r = (c.u + 0x7fffu + ((c.u >> 16) & 1u)) >> 16;
    return (u16)r;
}

__device__ inline void gld16(const void* g, void* l) {
    __builtin_amdgcn_global_load_lds(
        (const __attribute__((address_space(1))) void*)g,
        (__attribute__((address_space(3))) void*)l, 16, 0, 0);
}

__device__ inline bf16x8 negbf(bf16x8 v) {
    u32x4 u; __builtin_memcpy(&u, &v, 16);
    u ^= 0x80008000u;
    bf16x8 r; __builtin_memcpy(&r, &u, 16);
    return r;
}

// ---------------- f32 -> bf16 convert (8 elems/thread) ----------------
__global__ __launch_bounds__(256) void cvt_bf16(const float* __restrict__ s,
                                                u16* __restrict__ d) {
    size_t i = ((size_t)blockIdx.x * 256 + threadIdx.x) * 8;
    float4 v0 = *(const float4*)(s + i);
    float4 v1 = *(const float4*)(s + i + 4);
    bf16x8 o;
    o[0] = (short)f2bf(v0.x); o[1] = (short)f2bf(v0.y);
    o[2] = (short)f2bf(v0.z); o[3] = (short)f2bf(v0.w);
    o[4] = (short)f2bf(v1.x); o[5] = (short)f2bf(v1.y);
    o[6] = (short)f2bf(v1.z); o[7] = (short)f2bf(v1.w);
    *(bf16x8*)(d + i) = o;
}

// ---------------- transpose + convert: d[m][k] = bf16(s[k][m]) ----------------
__global__ __launch_bounds__(256) void tr_cvt(const float* __restrict__ s,
                                              u16* __restrict__ d) {
    __shared__ float t[32][33];
    int x  = blockIdx.x * 32 + threadIdx.x;   // src col
    int y0 = blockIdx.y * 32;                 // src row base
#pragma unroll
    for (int j = 0; j < 32; j += 8)
        t[threadIdx.y + j][threadIdx.x] = s[(size_t)(y0 + threadIdx.y + j) * NN + x];
    __syncthreads();
    int x2 = blockIdx.y * 32 + threadIdx.x;   // dst col (= src row)
    int y2 = blockIdx.x * 32;                 // dst row base (= src col)
#pragma unroll
    for (int j = 0; j < 32; j += 8)
        d[(size_t)(y2 + threadIdx.y + j) * NN + x2] = f2bf(t[threadIdx.x][threadIdx.y + j]);
}

// ---------------- pass 1: Rt = NT(W, x)  (two A's via blockIdx.z) ----------------
// out[i][j] = sum_k A[i][k] * B[j][k], all bf16 row-major [NN][NN], out bf16
__global__ __launch_bounds__(256) void gemm_nt_dual(
    const u16* __restrict__ A0, const u16* __restrict__ A1,
    const u16* __restrict__ B,
    u16* __restrict__ C0, u16* __restrict__ C1) {
    __shared__ u16 lA[128 * 32];
    __shared__ u16 lB[128 * 32];
    const u16* A = blockIdx.z ? A1 : A0;
    u16*       C = blockIdx.z ? C1 : C0;

    const int tid  = threadIdx.x;
    const int lane = tid & 63;
    const int wid  = tid >> 6;
    const int wm   = (wid >> 1) * 64;
    const int wn   = (wid & 1) * 64;
    const int brow = blockIdx.y * 128;
    const int bcol = blockIdx.x * 128;

    f32x4 acc[4][4] = {};

    const int r0 = tid >> 2;            // 0..63
    const int c0 = (tid & 3) * 8;       // 0,8,16,24
    const size_t aoff0 = (size_t)(brow + r0) * NN + c0;
    const size_t aoff1 = aoff0 + (size_t)64 * NN;
    const size_t boff0 = (size_t)(bcol + r0) * NN + c0;
    const size_t boff1 = boff0 + (size_t)64 * NN;
    const int rl = lane & 15;
    const int kg = (lane >> 4) * 8;

    for (int kk = 0; kk < NN; kk += 32) {
        gld16(A + aoff0 + kk, &lA[tid * 8]);
        gld16(A + aoff1 + kk, &lA[2048 + tid * 8]);
        gld16(B + boff0 + kk, &lB[tid * 8]);
        gld16(B + boff1 + kk, &lB[2048 + tid * 8]);
        __syncthreads();
        bf16x8 a[4], b[4];
#pragma unroll
        for (int i = 0; i < 4; i++)
            a[i] = *(const bf16x8*)&lA[(wm + i * 16 + rl) * 32 + kg];
#pragma unroll
        for (int j = 0; j < 4; j++)
            b[j] = *(const bf16x8*)&lB[(wn + j * 16 + rl) * 32 + kg];
#pragma unroll
        for (int i = 0; i < 4; i++)
#pragma unroll
            for (int j = 0; j < 4; j++)
                acc[i][j] = __builtin_amdgcn_mfma_f32_16x16x32_bf16(a[i], b[j], acc[i][j], 0, 0, 0);
        __syncthreads();
    }

    const int rg = (lane >> 4) * 4;
#pragma unroll
    for (int i = 0; i < 4; i++)
#pragma unroll
        for (int j = 0; j < 4; j++) {
            int col = bcol + wn + j * 16 + rl;
#pragma unroll
            for (int r = 0; r < 4; r++) {
                int row = brow + wm + i * 16 + rg + r;
                C[(size_t)row * NN + col] = f2bf(acc[i][j][r]);
            }
        }
}

// ---------------- pass 2: fused dual complex GEMM ----------------
// C_r[m,n] = sum_k Ar[m,k]Br[n,k] - Ai[m,k]Bi[n,k]
// C_i[m,n] = sum_k Ar[m,k]Bi[n,k] + Ai[m,k]Br[n,k]
// Out is f32 [NN][2*NN]; C_r at col n, C_i at col NN+n.
__global__ __launch_bounds__(256, 1) void gemm_pass2(
    const u16* __restrict__ Ar, const u16* __restrict__ Ai,
    const u16* __restrict__ Br, const u16* __restrict__ Bi,
    float* __restrict__ Out) {
    __shared__ u16 lAr[128 * 32];
    __shared__ u16 lAi[128 * 32];
    __shared__ u16 lBr[128 * 32];
    __shared__ u16 lBi[128 * 32];

    const int tid  = threadIdx.x;
    const int lane = tid & 63;
    const int wid  = tid >> 6;
    const int wm   = (wid >> 1) * 64;
    const int wn   = (wid & 1) * 64;
    const int brow = blockIdx.y * 128;
    const int bcol = blockIdx.x * 128;

    f32x4 accr[4][4] = {};
    f32x4 acci[4][4] = {};

    const int r0 = tid >> 2;
    const int c0 = (tid & 3) * 8;
    const size_t moff0 = (size_t)(brow + r0) * NN + c0;
    const size_t moff1 = moff0 + (size_t)64 * NN;
    const size_t noff0 = (size_t)(bcol + r0) * NN + c0;
    const size_t noff1 = noff0 + (size_t)64 * NN;
    const int rl = lane & 15;
    const int kg = (lane >> 4) * 8;

    for (int kk = 0; kk < NN; kk += 32) {
        gld16(Ar + moff0 + kk, &lAr[tid * 8]);
        gld16(Ar + moff1 + kk, &lAr[2048 + tid * 8]);
        gld16(Ai + moff0 + kk, &lAi[tid * 8]);
        gld16(Ai + moff1 + kk, &lAi[2048 + tid * 8]);
        gld16(Br + noff0 + kk, &lBr[tid * 8]);
        gld16(Br + noff1 + kk, &lBr[2048 + tid * 8]);
        gld16(Bi + noff0 + kk, &lBi[tid * 8]);
        gld16(Bi + noff1 + kk, &lBi[2048 + tid * 8]);
        __syncthreads();
        bf16x8 ar[4], ai[4], an[4], br[4], bi[4];
#pragma unroll
        for (int i = 0; i < 4; i++) {
            ar[i] = *(const bf16x8*)&lAr[(wm + i * 16 + rl) * 32 + kg];
            ai[i] = *(const bf16x8*)&lAi[(wm + i * 16 + rl) * 32 + kg];
            an[i] = negbf(ai[i]);
        }
#pragma unroll
        for (int j = 0; j < 4; j++) {
            br[j] = *(const bf16x8*)&lBr[(wn + j * 16 + rl) * 32 + kg];
            bi[j] = *(const bf16x8*)&lBi[(wn + j * 16 + rl) * 32 + kg];
        }
#pragma unroll
        for (int i = 0; i < 4; i++)
#pragma unroll
            for (int j = 0; j < 4; j++) {
                accr[i][j] = __builtin_amdgcn_mfma_f32_16x16x32_bf16(ar[i], br[j], accr[i][j], 0, 0, 0);
                accr[i][j] = __builtin_amdgcn_mfma_f32_16x16x32_bf16(an[i], bi[j], accr[i][j], 0, 0, 0);
                acci[i][j] = __builtin_amdgcn_mfma_f32_16x16x32_bf16(ar[i], bi[j], acci[i][j], 0, 0, 0);
                acci[i][j] = __builtin_amdgcn_mfma_f32_16x16x32_bf16(ai[i], br[j], acci[i][j], 0, 0, 0);
            }
        __syncthreads();
    }

    const int rg = (lane >> 4) * 4;
#pragma unroll
    for (int i = 0; i < 4; i++)
#pragma unroll
        for (int j = 0; j < 4; j++) {
            int col = bcol + wn + j * 16 + rl;
#pragma unroll
            for (int r = 0; r < 4; r++) {
                int row = brow + wm + i * 16 + rg + r;
                Out[(size_t)row * (2 * NN) + col]      = accr[i][j][r];
                Out[(size_t)row * (2 * NN) + NN + col] = acci[i][j][r];
            }
        }
}

extern "C" void kernel_launch(void* const* d_in, const int* in_sizes, int n_in,
                              void* d_out, int out_size, void* d_ws, size_t ws_size,
                              hipStream_t stream) {
    const float* x  = (const float*)d_in[0];
    const float* Wr = (const float*)d_in[1];
    const float* Wi = (const float*)d_in[2];
    float* out = (float*)d_out;

    const size_t SZ = (size_t)NN * NN;
    u16* ws  = (u16*)d_ws;
    u16* xb  = ws;            // slot 0: bf16 x        (later reused: WrT)
    u16* Wrb = ws + SZ;       // slot 1: bf16 W_r      (later reused: WiT)
    u16* Wib = ws + 2 * SZ;   // slot 2: bf16 W_i
    u16* Rtr = ws + 3 * SZ;   // slot 3: R_r^T bf16
    u16* Rti = ws + 4 * SZ;   // slot 4: R_i^T bf16

    // 1) convert inputs to bf16
    cvt_bf16<<<8192, 256, 0, stream>>>(x,  xb);
    cvt_bf16<<<8192, 256, 0, stream>>>(Wr, Wrb);
    cvt_bf16<<<8192, 256, 0, stream>>>(Wi, Wib);

    // 2) pass 1: Rt_r = NT(W_r, x), Rt_i = NT(W_i, x)
    gemm_nt_dual<<<dim3(32, 32, 2), 256, 0, stream>>>(Wrb, Wib, xb, Rtr, Rti);

    // 3) transposed bf16 weights (reuse slots 0,1 — xb/Wrb dead after pass 1)
    u16* WrT = xb;
    u16* WiT = Wrb;
    tr_cvt<<<dim3(128, 128), dim3(32, 8), 0, stream>>>(Wr, WrT);
    tr_cvt<<<dim3(128, 128), dim3(32, 8), 0, stream>>>(Wi, WiT);

    // 4) pass 2: fused dual complex GEMM -> d_out [NN][2*NN]
    gemm_pass2<<<dim3(32, 32), 256, 0, stream>>>(WrT, WiT, Rtr, Rti, out);
}

// Round 2
// 831.935 us; speedup vs baseline: 1.4982x; 1.4982x over previous
//
#include <hip/hip_runtime.h>
#include <hip/hip_bf16.h>

#define NN 4096

typedef unsigned short u16;
using bf16x8 = __attribute__((ext_vector_type(8))) short;
using f32x4  = __attribute__((ext_vector_type(4))) float;
using u32x4  = __attribute__((ext_vector_type(4))) unsigned int;

// round-to-nearest-even f32 -> bf16 bits
__device__ inline u16 f2bf(float f) {
    union { float f; unsigned u; } c; c.f = f;
    unsigned r = (c.u + 0x7fffu + ((c.u >> 16) & 1u)) >> 16;
    return (u16)r;
}

__device__ inline void gld16(const void* g, void* l) {
    __builtin_amdgcn_global_load_lds(
        (const __attribute__((address_space(1))) void*)g,
        (__attribute__((address_space(3))) void*)l, 16, 0, 0);
}

__device__ inline bf16x8 negbf(bf16x8 v) {
    u32x4 u; __builtin_memcpy(&u, &v, 16);
    u ^= 0x80008000u;
    bf16x8 r; __builtin_memcpy(&r, &u, 16);
    return r;
}

// ---------------- f32 -> bf16 convert (8 elems/thread) ----------------
__global__ __launch_bounds__(256) void cvt_bf16(const float* __restrict__ s,
                                                u16* __restrict__ d) {
    size_t i = ((size_t)blockIdx.x * 256 + threadIdx.x) * 8;
    float4 v0 = *(const float4*)(s + i);
    float4 v1 = *(const float4*)(s + i + 4);
    bf16x8 o;
    o[0] = (short)f2bf(v0.x); o[1] = (short)f2bf(v0.y);
    o[2] = (short)f2bf(v0.z); o[3] = (short)f2bf(v0.w);
    o[4] = (short)f2bf(v1.x); o[5] = (short)f2bf(v1.y);
    o[6] = (short)f2bf(v1.z); o[7] = (short)f2bf(v1.w);
    *(bf16x8*)(d + i) = o;
}

// ---------------- transpose + convert: d[m][k] = bf16(s[k][m]) ----------------
__global__ __launch_bounds__(256) void tr_cvt(const float* __restrict__ s,
                                              u16* __restrict__ d) {
    __shared__ float t[32][33];
    int x  = blockIdx.x * 32 + threadIdx.x;   // src col
    int y0 = blockIdx.y * 32;                 // src row base
#pragma unroll
    for (int j = 0; j < 32; j += 8)
        t[threadIdx.y + j][threadIdx.x] = s[(size_t)(y0 + threadIdx.y + j) * NN + x];
    __syncthreads();
    int x2 = blockIdx.y * 32 + threadIdx.x;   // dst col (= src row)
    int y2 = blockIdx.x * 32;                 // dst row base (= src col)
#pragma unroll
    for (int j = 0; j < 32; j += 8)
        d[(size_t)(y2 + threadIdx.y + j) * NN + x2] = f2bf(t[threadIdx.x][threadIdx.y + j]);
}

// ---------------- pass 1: Rt = NT(W, x)  (two A's via blockIdx.z) ----------------
// out[i][j] = sum_k A[i][k] * B[j][k], all bf16 row-major [NN][NN], out bf16
__global__ __launch_bounds__(256) void gemm_nt_dual(
    const u16* __restrict__ A0, const u16* __restrict__ A1,
    const u16* __restrict__ B,
    u16* __restrict__ C0, u16* __restrict__ C1) {
    __shared__ u16 lA[128 * 32];
    __shared__ u16 lB[128 * 32];
    const u16* A = blockIdx.z ? A1 : A0;
    u16*       C = blockIdx.z ? C1 : C0;

    const int tid  = threadIdx.x;
    const int lane = tid & 63;
    const int wid  = tid >> 6;
    const int wm   = (wid >> 1) * 64;
    const int wn   = (wid & 1) * 64;
    const int brow = blockIdx.y * 128;
    const int bcol = blockIdx.x * 128;

    f32x4 acc[4][4] = {};

    const int r0 = tid >> 2;            // 0..63
    const int c0 = (tid & 3) * 8;       // 0,8,16,24
    const size_t aoff0 = (size_t)(brow + r0) * NN + c0;
    const size_t aoff1 = aoff0 + (size_t)64 * NN;
    const size_t boff0 = (size_t)(bcol + r0) * NN + c0;
    const size_t boff1 = boff0 + (size_t)64 * NN;
    const int rl = lane & 15;
    const int kg = (lane >> 4) * 8;

    for (int kk = 0; kk < NN; kk += 32) {
        gld16(A + aoff0 + kk, &lA[tid * 8]);
        gld16(A + aoff1 + kk, &lA[2048 + tid * 8]);
        gld16(B + boff0 + kk, &lB[tid * 8]);
        gld16(B + boff1 + kk, &lB[2048 + tid * 8]);
        __syncthreads();
        bf16x8 a[4], b[4];
#pragma unroll
        for (int i = 0; i < 4; i++)
            a[i] = *(const bf16x8*)&lA[(wm + i * 16 + rl) * 32 + kg];
#pragma unroll
        for (int j = 0; j < 4; j++)
            b[j] = *(const bf16x8*)&lB[(wn + j * 16 + rl) * 32 + kg];
#pragma unroll
        for (int i = 0; i < 4; i++)
#pragma unroll
            for (int j = 0; j < 4; j++)
                acc[i][j] = __builtin_amdgcn_mfma_f32_16x16x32_bf16(a[i], b[j], acc[i][j], 0, 0, 0);
        __syncthreads();
    }

    const int rg = (lane >> 4) * 4;
#pragma unroll
    for (int i = 0; i < 4; i++)
#pragma unroll
        for (int j = 0; j < 4; j++) {
            int col = bcol + wn + j * 16 + rl;
#pragma unroll
            for (int r = 0; r < 4; r++) {
                int row = brow + wm + i * 16 + rg + r;
                C[(size_t)row * NN + col] = f2bf(acc[i][j][r]);
            }
        }
}

// ---------------- pass 2: fused dual complex GEMM ----------------
// C_r[m,n] = sum_k Ar[m,k]Br[n,k] - Ai[m,k]Bi[n,k]
// C_i[m,n] = sum_k Ar[m,k]Bi[n,k] + Ai[m,k]Br[n,k]
// Out is f32 [NN][2*NN]; C_r at col n, C_i at col NN+n.
// Register budget for 2 waves/SIMD: 128 acc (AGPR) + 64 frag + ~40 addr < 256.
__global__ __launch_bounds__(256, 2) void gemm_pass2(
    const u16* __restrict__ Ar, const u16* __restrict__ Ai,
    const u16* __restrict__ Br, const u16* __restrict__ Bi,
    float* __restrict__ Out) {
    __shared__ u16 lAr[128 * 32];
    __shared__ u16 lAi[128 * 32];
    __shared__ u16 lBr[128 * 32];
    __shared__ u16 lBi[128 * 32];

    const int tid  = threadIdx.x;
    const int lane = tid & 63;
    const int wid  = tid >> 6;
    const int wm   = (wid >> 1) * 64;
    const int wn   = (wid & 1) * 64;
    const int brow = blockIdx.y * 128;
    const int bcol = blockIdx.x * 128;

    f32x4 accr[4][4] = {};
    f32x4 acci[4][4] = {};

    const int r0 = tid >> 2;
    const int c0 = (tid & 3) * 8;
    const size_t moff0 = (size_t)(brow + r0) * NN + c0;
    const size_t moff1 = moff0 + (size_t)64 * NN;
    const size_t noff0 = (size_t)(bcol + r0) * NN + c0;
    const size_t noff1 = noff0 + (size_t)64 * NN;
    const int rl = lane & 15;
    const int kg = (lane >> 4) * 8;

    for (int kk = 0; kk < NN; kk += 32) {
        gld16(Ar + moff0 + kk, &lAr[tid * 8]);
        gld16(Ar + moff1 + kk, &lAr[2048 + tid * 8]);
        gld16(Ai + moff0 + kk, &lAi[tid * 8]);
        gld16(Ai + moff1 + kk, &lAi[2048 + tid * 8]);
        gld16(Br + noff0 + kk, &lBr[tid * 8]);
        gld16(Br + noff1 + kk, &lBr[2048 + tid * 8]);
        gld16(Bi + noff0 + kk, &lBi[tid * 8]);
        gld16(Bi + noff1 + kk, &lBi[2048 + tid * 8]);
        __syncthreads();
        bf16x8 ar[4], ai[4], br[4], bi[4];
#pragma unroll
        for (int i = 0; i < 4; i++) {
            ar[i] = *(const bf16x8*)&lAr[(wm + i * 16 + rl) * 32 + kg];
            ai[i] = *(const bf16x8*)&lAi[(wm + i * 16 + rl) * 32 + kg];
        }
#pragma unroll
        for (int j = 0; j < 4; j++) {
            br[j] = *(const bf16x8*)&lBr[(wn + j * 16 + rl) * 32 + kg];
            bi[j] = *(const bf16x8*)&lBi[(wn + j * 16 + rl) * 32 + kg];
        }
        // acci chain first (uses ai positive)
#pragma unroll
        for (int i = 0; i < 4; i++)
#pragma unroll
            for (int j = 0; j < 4; j++) {
                acci[i][j] = __builtin_amdgcn_mfma_f32_16x16x32_bf16(ar[i], bi[j], acci[i][j], 0, 0, 0);
                acci[i][j] = __builtin_amdgcn_mfma_f32_16x16x32_bf16(ai[i], br[j], acci[i][j], 0, 0, 0);
            }
        // negate ai in place, then accr chain
#pragma unroll
        for (int i = 0; i < 4; i++) ai[i] = negbf(ai[i]);
#pragma unroll
        for (int i = 0; i < 4; i++)
#pragma unroll
            for (int j = 0; j < 4; j++) {
                accr[i][j] = __builtin_amdgcn_mfma_f32_16x16x32_bf16(ar[i], br[j], accr[i][j], 0, 0, 0);
                accr[i][j] = __builtin_amdgcn_mfma_f32_16x16x32_bf16(ai[i], bi[j], accr[i][j], 0, 0, 0);
            }
        __syncthreads();
    }

    const int rg = (lane >> 4) * 4;
#pragma unroll
    for (int i = 0; i < 4; i++)
#pragma unroll
        for (int j = 0; j < 4; j++) {
            int col = bcol + wn + j * 16 + rl;
#pragma unroll
            for (int r = 0; r < 4; r++) {
                int row = brow + wm + i * 16 + rg + r;
                Out[(size_t)row * (2 * NN) + col]      = accr[i][j][r];
                Out[(size_t)row * (2 * NN) + NN + col] = acci[i][j][r];
            }
        }
}

extern "C" void kernel_launch(void* const* d_in, const int* in_sizes, int n_in,
                              void* d_out, int out_size, void* d_ws, size_t ws_size,
                              hipStream_t stream) {
    const float* x  = (const float*)d_in[0];
    const float* Wr = (const float*)d_in[1];
    const float* Wi = (const float*)d_in[2];
    float* out = (float*)d_out;

    const size_t SZ = (size_t)NN * NN;
    u16* ws  = (u16*)d_ws;
    u16* xb  = ws;            // slot 0: bf16 x        (later reused: WrT)
    u16* Wrb = ws + SZ;       // slot 1: bf16 W_r      (later reused: WiT)
    u16* Wib = ws + 2 * SZ;   // slot 2: bf16 W_i
    u16* Rtr = ws + 3 * SZ;   // slot 3: R_r^T bf16
    u16* Rti = ws + 4 * SZ;   // slot 4: R_i^T bf16

    // 1) convert inputs to bf16
    cvt_bf16<<<8192, 256, 0, stream>>>(x,  xb);
    cvt_bf16<<<8192, 256, 0, stream>>>(Wr, Wrb);
    cvt_bf16<<<8192, 256, 0, stream>>>(Wi, Wib);

    // 2) pass 1: Rt_r = NT(W_r, x), Rt_i = NT(W_i, x)
    gemm_nt_dual<<<dim3(32, 32, 2), 256, 0, stream>>>(Wrb, Wib, xb, Rtr, Rti);

    // 3) transposed bf16 weights (reuse slots 0,1 — xb/Wrb dead after pass 1)
    u16* WrT = xb;
    u16* WiT = Wrb;
    tr_cvt<<<dim3(128, 128), dim3(32, 8), 0, stream>>>(Wr, WrT);
    tr_cvt<<<dim3(128, 128), dim3(32, 8), 0, stream>>>(Wi, WiT);

    // 4) pass 2: fused dual complex GEMM -> d_out [NN][2*NN]
    gemm_pass2<<<dim3(32, 32), 256, 0, stream>>>(WrT, WiT, Rtr, Rti, out);
}